// Round 1
// baseline (113.708 us; speedup 1.0000x reference)
//
#include <hip/hip_runtime.h>
#include <hip/hip_bf16.h>

#define NN 1024   // batch
#define ND 512    // embed dim
#define NM 512    // prototypes

// ---------------------------------------------------------------------------
// Kernel 1: norms.  blocks [0, NN/4): ||x_row||^2, one wave per row.
//           blocks [NN/4, NN/4 + NM/256): ||p_col||^2, one thread per column.
// ---------------------------------------------------------------------------
__global__ __launch_bounds__(256) void norms_kernel(const float* __restrict__ X,
                                                    const float* __restrict__ P,
                                                    float* __restrict__ xx,
                                                    float* __restrict__ pp) {
    int bid = blockIdx.x;
    int tid = threadIdx.x;
    if (bid < NN / 4) {
        int wave = tid >> 6, lane = tid & 63;
        int row  = bid * 4 + wave;
        const float4* p = (const float4*)&X[row * ND + lane * 8];
        float4 v1 = p[0], v2 = p[1];
        float s = v1.x*v1.x + v1.y*v1.y + v1.z*v1.z + v1.w*v1.w
                + v2.x*v2.x + v2.y*v2.y + v2.z*v2.z + v2.w*v2.w;
        #pragma unroll
        for (int off = 32; off > 0; off >>= 1) s += __shfl_down(s, off, 64);
        if (lane == 0) xx[row] = s;
    } else {
        // P is (D, M) row-major; column sum over d: consecutive threads hit
        // consecutive m -> fully coalesced.
        int m = (bid - NN / 4) * 256 + tid;
        float s = 0.f;
        #pragma unroll 8
        for (int d = 0; d < ND; ++d) { float v = P[d * NM + m]; s = fmaf(v, v, s); }
        pp[m] = s;
    }
}

// ---------------------------------------------------------------------------
// Kernel 2: fused GEMM + epilogue.
// 64x64 output tile, BK=16, 256 threads (16x16), 4x4 micro-tile per thread.
// out[n,m] = -0.5*sqrt(max(xx[n] + pp[m] - 2*dot(x_n, p_m), 0))
// ---------------------------------------------------------------------------
#define BK 16

__global__ __launch_bounds__(256) void dist_kernel(const float* __restrict__ X,
                                                   const float* __restrict__ P,
                                                   const float* __restrict__ xx,
                                                   const float* __restrict__ pp,
                                                   float* __restrict__ out) {
    // Xs stored transposed [k][n], +4 pad keeps float4 alignment (stride 68*4B,
    // 16B-multiple) and reduces write conflicts to 2-way (free).
    __shared__ float Xs[BK][64 + 4];
    __shared__ float Ps[BK][64];

    int tid = threadIdx.x;
    int tx = tid & 15;        // m direction (x4)
    int ty = tid >> 4;        // n direction (x4)
    int n0 = blockIdx.y * 64;
    int m0 = blockIdx.x * 64;

    int lr = tid >> 2;            // X-load: row within tile (0..63)
    int lk = (tid & 3) * 4;       // X-load: k quad (0,4,8,12)
    int pk = tid >> 6;            // P-load: k row (0..3)
    int pm = tid & 63;            // P-load: m (0..63)

    float acc[4][4] = {};

    for (int k0 = 0; k0 < ND; k0 += BK) {
        float4 v = *(const float4*)&X[(n0 + lr) * ND + k0 + lk];
        Xs[lk + 0][lr] = v.x;
        Xs[lk + 1][lr] = v.y;
        Xs[lk + 2][lr] = v.z;
        Xs[lk + 3][lr] = v.w;
        #pragma unroll
        for (int p = 0; p < 4; ++p)
            Ps[pk + p * 4][pm] = P[(k0 + pk + p * 4) * NM + m0 + pm];
        __syncthreads();

        #pragma unroll
        for (int k = 0; k < BK; ++k) {
            float4 a = *(const float4*)&Xs[k][ty * 4];
            float4 b = *(const float4*)&Ps[k][tx * 4];
            float av[4] = {a.x, a.y, a.z, a.w};
            float bv[4] = {b.x, b.y, b.z, b.w};
            #pragma unroll
            for (int i = 0; i < 4; ++i)
                #pragma unroll
                for (int j = 0; j < 4; ++j)
                    acc[i][j] = fmaf(av[i], bv[j], acc[i][j]);
        }
        __syncthreads();
    }

    // epilogue: -0.5*sqrt(xx + pp - 2*dot), float4 stores
    float pv[4];
    #pragma unroll
    for (int j = 0; j < 4; ++j) pv[j] = pp[m0 + tx * 4 + j];
    #pragma unroll
    for (int i = 0; i < 4; ++i) {
        float xn = xx[n0 + ty * 4 + i];
        float4 o;
        o.x = -0.5f * sqrtf(fmaxf(xn + pv[0] - 2.f * acc[i][0], 0.f));
        o.y = -0.5f * sqrtf(fmaxf(xn + pv[1] - 2.f * acc[i][1], 0.f));
        o.z = -0.5f * sqrtf(fmaxf(xn + pv[2] - 2.f * acc[i][2], 0.f));
        o.w = -0.5f * sqrtf(fmaxf(xn + pv[3] - 2.f * acc[i][3], 0.f));
        *(float4*)&out[(n0 + ty * 4 + i) * NM + m0 + tx * 4] = o;
    }
}

extern "C" void kernel_launch(void* const* d_in, const int* in_sizes, int n_in,
                              void* d_out, int out_size, void* d_ws, size_t ws_size,
                              hipStream_t stream) {
    const float* x     = (const float*)d_in[0];   // (N, D)
    const float* proto = (const float*)d_in[1];   // (D, M)
    float* xx  = (float*)d_ws;        // NN floats
    float* pp  = xx + NN;             // NM floats
    float* out = (float*)d_out;       // (N, M)

    hipLaunchKernelGGL(norms_kernel, dim3(NN / 4 + NM / 256), dim3(256), 0, stream,
                       x, proto, xx, pp);
    hipLaunchKernelGGL(dist_kernel, dim3(NM / 64, NN / 64), dim3(256), 0, stream,
                       x, proto, xx, pp, out);
}

// Round 3
// 64.212 us; speedup vs baseline: 1.7708x; 1.7708x over previous
//
#include <hip/hip_runtime.h>
#include <hip/hip_bf16.h>

#define NN 1024   // batch
#define ND 512    // embed dim (K)
#define NM 512    // prototypes

typedef __attribute__((ext_vector_type(8))) short short8;   // 8 bf16 = 4 VGPR (MFMA A/B frag)
typedef __attribute__((ext_vector_type(4))) float f32x4;    // MFMA C/D frag

__device__ __forceinline__ ushort f2bf(float f) {           // f32 -> bf16 RNE
    union { float f; unsigned u; } v; v.f = f;
    unsigned r = v.u + 0x7FFFu + ((v.u >> 16) & 1u);
    return (ushort)(r >> 16);
}
__device__ __forceinline__ float bflo(unsigned u) { union { unsigned u; float f; } v; v.u = u << 16;         return v.f; }
__device__ __forceinline__ float bfhi(unsigned u) { union { unsigned u; float f; } v; v.u = u & 0xFFFF0000u; return v.f; }

// ---------------------------------------------------------------------------
// prep: transpose P (k,m) f32 -> Pt (m,k) bf16, 64x64 tiles via padded LDS.
// Makes the GEMM's B operand k-contiguous so B-frags are single ds_read_b128.
// ---------------------------------------------------------------------------
__global__ __launch_bounds__(256) void prep_kernel(const float* __restrict__ P,
                                                   ushort* __restrict__ Pt) {
    __shared__ float Ls[64][65];                 // +1 pad: conflict-free column reads
    const int t  = threadIdx.x;
    const int m0 = (blockIdx.x & 7) * 64;
    const int k0 = (blockIdx.x >> 3) * 64;
    {
        const int r = t >> 2, q = t & 3;         // row, m-quad
        const float* src = P + (k0 + r) * NM + m0 + q * 4;
        #pragma unroll
        for (int j = 0; j < 4; ++j) {
            float4 v = *(const float4*)(src + j * 16);
            *(float4*)&Ls[r][q * 4 + j * 16] = v;
        }
    }
    __syncthreads();
    {
        const int m = t >> 2, kq = (t & 3) * 16; // each thread: 16 k of one m-row
        unsigned w[8];
        #pragma unroll
        for (int i = 0; i < 8; ++i)
            w[i] = (unsigned)f2bf(Ls[kq + 2 * i][m]) |
                   ((unsigned)f2bf(Ls[kq + 2 * i + 1][m]) << 16);
        ushort* dst = Pt + (m0 + m) * ND + k0 + kq;
        *(uint4*)(dst)     = make_uint4(w[0], w[1], w[2], w[3]);
        *(uint4*)(dst + 8) = make_uint4(w[4], w[5], w[6], w[7]);
    }
}

// ---------------------------------------------------------------------------
// main: out[n,m] = -0.5*sqrt(xx[n] + pp[m] - 2*dot(x_n, p_m))
// 32n x 64m tile, 256 blocks (all CUs), 4 waves 2x2, BK=64,
// mfma_f32_16x16x32_bf16, norms fused into staging, 1 barrier/step dbuf.
// ---------------------------------------------------------------------------
__global__ __launch_bounds__(256) void dist_kernel(const float* __restrict__ X,
                                                   const ushort* __restrict__ Pt,
                                                   float* __restrict__ out) {
    // 72-elem rows (144B): 16B-aligned chunks, uniform bank spread for b128
    __shared__ ushort As[2][32][72];
    __shared__ ushort Bs[2][64][72];
    __shared__ float  xx_s[32];
    __shared__ float  pp_s[64];

    const int t  = threadIdx.x;
    const int n0 = blockIdx.y * 32;
    const int m0 = blockIdx.x * 64;

    const int sr = t >> 3;      // staging row (0..31)
    const int sk = t & 7;       // staging k-block (k = sk*8)

    const float*  ax  = X  + (n0 + sr) * ND + sk * 8;        // f32 X chunk
    const ushort* bp1 = Pt + (m0 + sr) * ND + sk * 8;        // bf16 Pt chunks
    const ushort* bp2 = Pt + (m0 + 32 + sr) * ND + sk * 8;

    const int lane = t & 63;
    const int wid  = t >> 6;
    const int wn = wid >> 1, wm = wid & 1;   // wave quadrant: 16n x 32m
    const int fr = lane & 15, fq = lane >> 4;

    float xacc = 0.f, pacc1 = 0.f, pacc2 = 0.f;
    f32x4 acc0 = {0.f, 0.f, 0.f, 0.f};
    f32x4 acc1 = {0.f, 0.f, 0.f, 0.f};

    // prologue loads (step 0)
    float4 a0 = *(const float4*)(ax);
    float4 a1 = *(const float4*)(ax + 4);
    uint4  q1 = *(const uint4*)(bp1);
    uint4  q2 = *(const uint4*)(bp2);

    for (int step = 0; step < 8; ++step) {
        const int buf = step & 1;

        // stage current regs -> LDS[buf]; fold norm partials (f32 for X, bf16 for P)
        xacc = fmaf(a0.x, a0.x, xacc); xacc = fmaf(a0.y, a0.y, xacc);
        xacc = fmaf(a0.z, a0.z, xacc); xacc = fmaf(a0.w, a0.w, xacc);
        xacc = fmaf(a1.x, a1.x, xacc); xacc = fmaf(a1.y, a1.y, xacc);
        xacc = fmaf(a1.z, a1.z, xacc); xacc = fmaf(a1.w, a1.w, xacc);
        {
            unsigned w0 = (unsigned)f2bf(a0.x) | ((unsigned)f2bf(a0.y) << 16);
            unsigned w1 = (unsigned)f2bf(a0.z) | ((unsigned)f2bf(a0.w) << 16);
            unsigned w2 = (unsigned)f2bf(a1.x) | ((unsigned)f2bf(a1.y) << 16);
            unsigned w3 = (unsigned)f2bf(a1.z) | ((unsigned)f2bf(a1.w) << 16);
            *(uint4*)&As[buf][sr][sk * 8] = make_uint4(w0, w1, w2, w3);
        }
        *(uint4*)&Bs[buf][sr][sk * 8]      = q1;
        *(uint4*)&Bs[buf][32 + sr][sk * 8] = q2;
        {
            float v;
            v = bflo(q1.x); pacc1 = fmaf(v, v, pacc1); v = bfhi(q1.x); pacc1 = fmaf(v, v, pacc1);
            v = bflo(q1.y); pacc1 = fmaf(v, v, pacc1); v = bfhi(q1.y); pacc1 = fmaf(v, v, pacc1);
            v = bflo(q1.z); pacc1 = fmaf(v, v, pacc1); v = bfhi(q1.z); pacc1 = fmaf(v, v, pacc1);
            v = bflo(q1.w); pacc1 = fmaf(v, v, pacc1); v = bfhi(q1.w); pacc1 = fmaf(v, v, pacc1);
            v = bflo(q2.x); pacc2 = fmaf(v, v, pacc2); v = bfhi(q2.x); pacc2 = fmaf(v, v, pacc2);
            v = bflo(q2.y); pacc2 = fmaf(v, v, pacc2); v = bfhi(q2.y); pacc2 = fmaf(v, v, pacc2);
            v = bflo(q2.z); pacc2 = fmaf(v, v, pacc2); v = bfhi(q2.z); pacc2 = fmaf(v, v, pacc2);
            v = bflo(q2.w); pacc2 = fmaf(v, v, pacc2); v = bfhi(q2.w); pacc2 = fmaf(v, v, pacc2);
        }

        // prefetch next step (latency hides under barrier + MFMA phase)
        if (step < 7) {
            const float* p = ax + (step + 1) * 64;
            a0 = *(const float4*)(p);
            a1 = *(const float4*)(p + 4);
            q1 = *(const uint4*)(bp1 + (step + 1) * 64);
            q2 = *(const uint4*)(bp2 + (step + 1) * 64);
        }

        __syncthreads();   // LDS[buf] ready; also fences buf^1 reuse (see dbuf proof)

        #pragma unroll
        for (int s = 0; s < 2; ++s) {
            const int kk = s * 32 + fq * 8;
            short8 af  = *(const short8*)&As[buf][wn * 16 + fr][kk];
            short8 bf0 = *(const short8*)&Bs[buf][wm * 32 + fr][kk];
            short8 bf1 = *(const short8*)&Bs[buf][wm * 32 + 16 + fr][kk];
            acc0 = __builtin_amdgcn_mfma_f32_16x16x32_bf16(af, bf0, acc0, 0, 0, 0);
            acc1 = __builtin_amdgcn_mfma_f32_16x16x32_bf16(af, bf1, acc1, 0, 0, 0);
        }
    }

    // reduce norm partials: 8 threads (sk=0..7) per row, contiguous lanes
    #pragma unroll
    for (int off = 4; off > 0; off >>= 1) {
        xacc  += __shfl_down(xacc,  off, 8);
        pacc1 += __shfl_down(pacc1, off, 8);
        pacc2 += __shfl_down(pacc2, off, 8);
    }
    if (sk == 0) { xx_s[sr] = xacc; pp_s[sr] = pacc1; pp_s[sr + 32] = pacc2; }
    __syncthreads();

    // epilogue: C/D layout col=lane&15, row=(lane>>4)*4+reg  [m89/m91]
    const float pv0 = pp_s[wm * 32 + fr];
    const float pv1 = pp_s[wm * 32 + 16 + fr];
    float* orow = out + (n0 + wn * 16) * NM + m0 + wm * 32 + fr;
    #pragma unroll
    for (int r = 0; r < 4; ++r) {
        const int rowl = fq * 4 + r;
        const float xv = xx_s[wn * 16 + rowl];
        orow[rowl * NM]      = -0.5f * sqrtf(fmaxf(xv + pv0 - 2.f * acc0[r], 0.f));
        orow[rowl * NM + 16] = -0.5f * sqrtf(fmaxf(xv + pv1 - 2.f * acc1[r], 0.f));
    }
}

extern "C" void kernel_launch(void* const* d_in, const int* in_sizes, int n_in,
                              void* d_out, int out_size, void* d_ws, size_t ws_size,
                              hipStream_t stream) {
    const float* x     = (const float*)d_in[0];   // (N, D) f32
    const float* proto = (const float*)d_in[1];   // (D, M) f32
    ushort* Pt = (ushort*)d_ws;                   // (M, D) bf16, 512 KB
    float*  out = (float*)d_out;                  // (N, M) f32

    hipLaunchKernelGGL(prep_kernel, dim3(64), dim3(256), 0, stream, proto, Pt);
    hipLaunchKernelGGL(dist_kernel, dim3(NM / 64, NN / 32), dim3(256), 0, stream,
                       x, Pt, out);
}

// Round 4
// 64.055 us; speedup vs baseline: 1.7752x; 1.0025x over previous
//
#include <hip/hip_runtime.h>
#include <hip/hip_bf16.h>

#define NN 1024   // batch
#define ND 512    // embed dim (K)
#define NM 512    // prototypes

typedef __attribute__((ext_vector_type(8))) short short8;   // 8 bf16 = 4 VGPR (MFMA A/B frag)
typedef __attribute__((ext_vector_type(4))) float f32x4;    // MFMA C/D frag

__device__ __forceinline__ ushort f2bf(float f) {           // f32 -> bf16 RNE
    union { float f; unsigned u; } v; v.f = f;
    unsigned r = v.u + 0x7FFFu + ((v.u >> 16) & 1u);
    return (ushort)(r >> 16);
}

// ---------------------------------------------------------------------------
// Single fused kernel: out[n,m] = -0.5*sqrt(xx[n] + pp[m] - 2*dot(x_n, p_m))
// 32n x 64m tile, 256 blocks (1/CU), 4 waves 2x2, BK=64,
// mfma_f32_16x16x32_bf16. P is transposed in-flight: each thread owns one
// m-column, reads 16 k-consecutive f32 (coalesced along m across the wave),
// packs to bf16, writes one k-contiguous b128 pair into Bs. Norms fused into
// staging (f32, pre-convert). 1 barrier/step double-buffer (race-free: stage
// s+1 writes buf^1 while MFMA s reads buf; buf reuse separated by 2 barriers).
// ---------------------------------------------------------------------------
__global__ __launch_bounds__(256) void fused_kernel(const float* __restrict__ X,
                                                    const float* __restrict__ P,
                                                    float* __restrict__ out) {
    // 72-elem rows (144B): 16B-aligned chunks, uniform bank spread for b128
    __shared__ ushort As[2][32][72];
    __shared__ ushort Bs[2][64][72];
    __shared__ float  xx_s[32];
    __shared__ float  pp_part[4][64];

    const int t  = threadIdx.x;
    const int n0 = blockIdx.y * 32;
    const int m0 = blockIdx.x * 64;

    // X staging: row sr (0..31), k-octet sk (0..7)
    const int sr = t >> 3;
    const int sk = t & 7;
    const float* ax = X + (n0 + sr) * ND + sk * 8;

    // P staging: m-column pm (0..63), k-quarter pq (0..3) -> 16 k per step
    const int pm = t & 63;
    const int pq = t >> 6;
    const float* bp = P + (pq * 16) * NM + m0 + pm;   // + (step*64 + j)*NM

    const int lane = t & 63;
    const int wid  = t >> 6;
    const int wn = wid >> 1, wm = wid & 1;   // wave quadrant: 16n x 32m
    const int fr = lane & 15, fq = lane >> 4;

    float xacc = 0.f, pacc = 0.f;
    f32x4 acc0 = {0.f, 0.f, 0.f, 0.f};
    f32x4 acc1 = {0.f, 0.f, 0.f, 0.f};

    // prologue loads (step 0)
    float4 a0 = *(const float4*)(ax);
    float4 a1 = *(const float4*)(ax + 4);
    float  b[16];
    #pragma unroll
    for (int j = 0; j < 16; ++j) b[j] = bp[j * NM];

    for (int step = 0; step < 8; ++step) {
        const int buf = step & 1;

        // ---- stage X: fold norm (f32), convert, one b128 write
        xacc = fmaf(a0.x, a0.x, xacc); xacc = fmaf(a0.y, a0.y, xacc);
        xacc = fmaf(a0.z, a0.z, xacc); xacc = fmaf(a0.w, a0.w, xacc);
        xacc = fmaf(a1.x, a1.x, xacc); xacc = fmaf(a1.y, a1.y, xacc);
        xacc = fmaf(a1.z, a1.z, xacc); xacc = fmaf(a1.w, a1.w, xacc);
        {
            unsigned w0 = (unsigned)f2bf(a0.x) | ((unsigned)f2bf(a0.y) << 16);
            unsigned w1 = (unsigned)f2bf(a0.z) | ((unsigned)f2bf(a0.w) << 16);
            unsigned w2 = (unsigned)f2bf(a1.x) | ((unsigned)f2bf(a1.y) << 16);
            unsigned w3 = (unsigned)f2bf(a1.z) | ((unsigned)f2bf(a1.w) << 16);
            *(uint4*)&As[buf][sr][sk * 8] = make_uint4(w0, w1, w2, w3);
        }

        // ---- stage P: fold norm (f32), pack 16 k-consecutive bf16, 2 b128 writes
        {
            #pragma unroll
            for (int j = 0; j < 16; ++j) pacc = fmaf(b[j], b[j], pacc);
            unsigned w[8];
            #pragma unroll
            for (int i = 0; i < 8; ++i)
                w[i] = (unsigned)f2bf(b[2 * i]) | ((unsigned)f2bf(b[2 * i + 1]) << 16);
            *(uint4*)&Bs[buf][pm][pq * 16]     = make_uint4(w[0], w[1], w[2], w[3]);
            *(uint4*)&Bs[buf][pm][pq * 16 + 8] = make_uint4(w[4], w[5], w[6], w[7]);
        }

        // ---- prefetch next step (hides under barrier + MFMA phase)
        if (step < 7) {
            const float* p = ax + (step + 1) * 64;
            a0 = *(const float4*)(p);
            a1 = *(const float4*)(p + 4);
            const float* q = bp + (step + 1) * 64 * NM;
            #pragma unroll
            for (int j = 0; j < 16; ++j) b[j] = q[j * NM];
        }

        __syncthreads();   // LDS[buf] ready

        #pragma unroll
        for (int s = 0; s < 2; ++s) {
            const int kk = s * 32 + fq * 8;
            short8 af  = *(const short8*)&As[buf][wn * 16 + fr][kk];
            short8 bf0 = *(const short8*)&Bs[buf][wm * 32 + fr][kk];
            short8 bf1 = *(const short8*)&Bs[buf][wm * 32 + 16 + fr][kk];
            acc0 = __builtin_amdgcn_mfma_f32_16x16x32_bf16(af, bf0, acc0, 0, 0, 0);
            acc1 = __builtin_amdgcn_mfma_f32_16x16x32_bf16(af, bf1, acc1, 0, 0, 0);
        }
    }

    // ---- norm reductions
    // xx: 8 threads (sk=0..7, consecutive lanes) per row
    #pragma unroll
    for (int off = 4; off > 0; off >>= 1) xacc += __shfl_down(xacc, off, 8);
    if (sk == 0) xx_s[sr] = xacc;
    // pp: 4 k-quarter partials per m-column, cross-wave via LDS
    pp_part[pq][pm] = pacc;
    __syncthreads();

    // ---- epilogue: C/D layout col=lane&15, row=(lane>>4)*4+reg  [m89/m91]
    const int c0 = wm * 32 + fr, c1 = wm * 32 + 16 + fr;
    const float pv0 = pp_part[0][c0] + pp_part[1][c0] + pp_part[2][c0] + pp_part[3][c0];
    const float pv1 = pp_part[0][c1] + pp_part[1][c1] + pp_part[2][c1] + pp_part[3][c1];
    float* orow = out + (n0 + wn * 16) * NM + m0 + wm * 32 + fr;
    #pragma unroll
    for (int r = 0; r < 4; ++r) {
        const int rowl = fq * 4 + r;
        const float xv = xx_s[wn * 16 + rowl];
        orow[rowl * NM]      = -0.5f * sqrtf(fmaxf(xv + pv0 - 2.f * acc0[r], 0.f));
        orow[rowl * NM + 16] = -0.5f * sqrtf(fmaxf(xv + pv1 - 2.f * acc1[r], 0.f));
    }
}

extern "C" void kernel_launch(void* const* d_in, const int* in_sizes, int n_in,
                              void* d_out, int out_size, void* d_ws, size_t ws_size,
                              hipStream_t stream) {
    const float* x     = (const float*)d_in[0];   // (N, D) f32
    const float* proto = (const float*)d_in[1];   // (D, M) f32
    float* out = (float*)d_out;                   // (N, M) f32
    hipLaunchKernelGGL(fused_kernel, dim3(NM / 64, NN / 32), dim3(256), 0, stream,
                       x, proto, out);
}

// Round 8
// 62.049 us; speedup vs baseline: 1.8326x; 1.0323x over previous
//
#include <hip/hip_runtime.h>
#include <hip/hip_bf16.h>

#define NN 1024   // batch
#define ND 512    // embed dim (K)
#define NM 512    // prototypes

typedef __attribute__((ext_vector_type(8))) short short8;   // 8 bf16 = 4 VGPR (MFMA A/B frag)
typedef __attribute__((ext_vector_type(4))) float f32x4;    // MFMA C/D frag

__device__ __forceinline__ ushort f2bf(float f) {           // f32 -> bf16 RNE
    union { float f; unsigned u; } v; v.f = f;
    unsigned r = v.u + 0x7FFFu + ((v.u >> 16) & 1u);
    return (ushort)(r >> 16);
}

// ---------------------------------------------------------------------------
// out[n,m] = -0.5*sqrt(xx[n] + pp[m] - 2*dot(x_n, p_m))
// 32n x 64m tile, 256 blocks, 512 threads (8 waves, 2/SIMD), BK=64,
// mfma_f32_16x16x32_bf16, one 16x16 frag per wave (2x4 wave grid).
// P transposed in-flight (coalesced along m); norms fused into staging.
// Early prefetch + reg dbuf: loads issue at step-top so staging VALU covers
// L2 latency before the compiler's vmcnt(0)-before-barrier drain.
// Grid is (n-tiles, m-tiles) so id%8 = n-tile%8: each XCD gets 4 X-slabs
// (256KB, 8x L2 reuse) + full P (1MB) -> 1.25MB/XCD working set.
// ---------------------------------------------------------------------------
__global__ __launch_bounds__(512) void fused_kernel(const float* __restrict__ X,
                                                    const float* __restrict__ P,
                                                    float* __restrict__ out) {
    // 72-elem rows (144B): 16B-aligned chunks, >=2-way-only bank aliasing (free)
    __shared__ ushort As[2][32][72];
    __shared__ ushort Bs[2][64][72];
    __shared__ float  xx_s[32];
    __shared__ float  pp_part[8][64];

    const int t  = threadIdx.x;
    const int n0 = blockIdx.x * 32;   // grid.x = n-tiles (XCD locality)
    const int m0 = blockIdx.y * 64;   // grid.y = m-tiles

    // X staging: row sr (0..31), k-quad sk (0..15) -> one float4 per step
    const int sr = t >> 4;
    const int sk = t & 15;
    const float* ax = X + (n0 + sr) * ND + sk * 4;

    // P staging: m-column pm (0..63), k-octet pk (0..7) -> 8 strided f32 per step
    const int pm = t & 63;
    const int pk = t >> 6;
    const float* bp = P + (pk * 8) * NM + m0 + pm;

    const int lane = t & 63;
    const int wid  = t >> 6;          // 0..7
    const int wn   = wid >> 2;        // 0..1  (16n quadrant)
    const int wm   = wid & 3;         // 0..3  (16m quadrant)
    const int fr = lane & 15, fq = lane >> 4;

    float xacc = 0.f, pacc = 0.f;
    f32x4 acc = {0.f, 0.f, 0.f, 0.f};

    float4 a[2];
    float  b[2][8];

    // prologue loads (step 0)
    a[0] = *(const float4*)ax;
    #pragma unroll
    for (int j = 0; j < 8; ++j) b[0][j] = bp[j * NM];

    #pragma unroll
    for (int step = 0; step < 8; ++step) {
        const int cur = step & 1, nxt = cur ^ 1;

        // ---- early prefetch: issue next-step loads FIRST (staging VALU covers)
        if (step < 7) {
            const float* pax = ax + (step + 1) * 64;
            a[nxt] = *(const float4*)pax;
            const float* pbp = bp + (step + 1) * 64 * NM;
            #pragma unroll
            for (int j = 0; j < 8; ++j) b[nxt][j] = pbp[j * NM];
        }

        // ---- stage X: fold norm (f32), convert, b64 write
        {
            float4 av = a[cur];
            xacc = fmaf(av.x, av.x, xacc); xacc = fmaf(av.y, av.y, xacc);
            xacc = fmaf(av.z, av.z, xacc); xacc = fmaf(av.w, av.w, xacc);
            uint2 xw;
            xw.x = (unsigned)f2bf(av.x) | ((unsigned)f2bf(av.y) << 16);
            xw.y = (unsigned)f2bf(av.z) | ((unsigned)f2bf(av.w) << 16);
            *(uint2*)&As[cur][sr][sk * 4] = xw;
        }

        // ---- stage P: fold norm (f32), pack 8 k-consecutive bf16, b128 write
        {
            unsigned w[4];
            #pragma unroll
            for (int i = 0; i < 4; ++i) {
                float lo = b[cur][2 * i], hi = b[cur][2 * i + 1];
                pacc = fmaf(lo, lo, pacc); pacc = fmaf(hi, hi, pacc);
                w[i] = (unsigned)f2bf(lo) | ((unsigned)f2bf(hi) << 16);
            }
            *(uint4*)&Bs[cur][pm][pk * 8] = make_uint4(w[0], w[1], w[2], w[3]);
        }

        __syncthreads();   // LDS[cur] ready (1 barrier/step dbuf, race-free)

        #pragma unroll
        for (int s = 0; s < 2; ++s) {
            const int kk = s * 32 + fq * 8;
            short8 af = *(const short8*)&As[cur][wn * 16 + fr][kk];
            short8 bf = *(const short8*)&Bs[cur][wm * 16 + fr][kk];
            acc = __builtin_amdgcn_mfma_f32_16x16x32_bf16(af, bf, acc, 0, 0, 0);
        }
    }

    // ---- norm reductions
    #pragma unroll
    for (int off = 8; off > 0; off >>= 1) xacc += __shfl_down(xacc, off, 16);
    if (sk == 0) xx_s[sr] = xacc;
    pp_part[pk][pm] = pacc;
    __syncthreads();

    // ---- epilogue: C/D layout col=lane&15, row=(lane>>4)*4+reg  [m89/m91]
    const int col = wm * 16 + fr;
    float pv = 0.f;
    #pragma unroll
    for (int i = 0; i < 8; ++i) pv += pp_part[i][col];
    float* orow = out + (n0 + wn * 16) * NM + m0 + col;
    #pragma unroll
    for (int r = 0; r < 4; ++r) {
        const int rowl = fq * 4 + r;
        const float xv = xx_s[wn * 16 + rowl];
        orow[rowl * NM] = -0.5f * sqrtf(fmaxf(xv + pv - 2.f * acc[r], 0.f));
    }
}

extern "C" void kernel_launch(void* const* d_in, const int* in_sizes, int n_in,
                              void* d_out, int out_size, void* d_ws, size_t ws_size,
                              hipStream_t stream) {
    const float* x     = (const float*)d_in[0];   // (N, D) f32
    const float* proto = (const float*)d_in[1];   // (D, M) f32
    float* out = (float*)d_out;                   // (N, M) f32
    hipLaunchKernelGGL(fused_kernel, dim3(NN / 32, NM / 64), dim3(512), 0, stream,
                       x, proto, out);
}